// Round 11
// baseline (122.064 us; speedup 1.0000x reference)
//
#include <hip/hip_runtime.h>
#include <hip/hip_bf16.h>

typedef __attribute__((ext_vector_type(8))) short short8_t;
typedef __attribute__((ext_vector_type(4))) short s4v;
typedef __attribute__((ext_vector_type(4))) float f32x4_t;
typedef __attribute__((ext_vector_type(4))) unsigned u32x4_t;
using u16 = unsigned short;

constexpr int S_LEN = 2048;
constexpr int EMB   = 1024;
constexpr int NH    = 16;
constexpr int HD    = 64;
constexpr int BATCH = 2;
constexpr int MR    = BATCH * S_LEN;  // 4096
constexpr int E3    = 3 * EMB;        // 3072

#define L2E 1.44269504f

__device__ __forceinline__ u16 f2bf(float f) {
  unsigned u = __builtin_bit_cast(unsigned, f);
  unsigned r = 0x7fffu + ((u >> 16) & 1u);
  return (u16)((u + r) >> 16);
}

// packed f32x2 -> bf16x2 via intrinsic (RNE, compiler emits v_cvt_pk_bf16_f32)
__device__ __forceinline__ unsigned pkbf(float a, float b) {
  __hip_bfloat162 h = __float22bfloat162_rn(make_float2(a, b));
  unsigned u;
  __builtin_memcpy(&u, &h, 4);
  return u;
}

__device__ __forceinline__ void gld16(const void* g, void* l) {
  __builtin_amdgcn_global_load_lds(
      (const __attribute__((address_space(1))) void*)g,
      (__attribute__((address_space(3))) void*)l, 16, 0, 0);
}

// hardware transpose read. Canonical per-lane address = base + 8B*lane:
// lane l, elem j <- lds_elem[64*(l>>4) + 16*j + (l&15)] (+ offset/2 elems).
template <int OFF>
__device__ __forceinline__ s4v tr16(const __attribute__((address_space(3))) u16* p) {
  s4v d;
  asm volatile("ds_read_b64_tr_b16 %0, %1 offset:%2"
               : "=v"(d) : "v"(p), "n"(OFF));
  return d;
}

// ---------------- fused fp32 -> bf16 conversion ----------------------------
// dest layout (contiguous in ws): xb(4M) | Wq(1M,*0.125) | Wk | Wv | Wo
__global__ void k_cvt_all(const float* __restrict__ x, const float* __restrict__ Wq,
                          const float* __restrict__ Wk, const float* __restrict__ Wv,
                          const float* __restrict__ Wo, u16* __restrict__ out) {
  int i = blockIdx.x * 256 + threadIdx.x;  // float4 index, total 2M
  const float* src;
  int j;
  float sc = 1.0f;
  if (i < (1 << 20)) {
    src = x; j = i;
  } else {
    int jj = i - (1 << 20);
    int r = jj >> 18;
    j = jj & ((1 << 18) - 1);
    src = (r == 0) ? Wq : (r == 1) ? Wk : (r == 2) ? Wv : Wo;
    if (r == 0) sc = 0.125f;  // fold softmax 1/sqrt(64)
  }
  float4 v = reinterpret_cast<const float4*>(src)[j];
  ushort4 o;
  o.x = f2bf(v.x * sc); o.y = f2bf(v.y * sc);
  o.z = f2bf(v.z * sc); o.w = f2bf(v.w * sc);
  reinterpret_cast<ushort4*>(out)[i] = o;
}

// ---------------- bf16 GEMM, B^T input (C = A @ B^T), 128x128 tile ---------
// 2-phase double-buffered staging (r9-verified). T1 XCD swizzle.
template <bool F32OUT>
__global__ __launch_bounds__(256) void k_gemm_bt(
    const u16* __restrict__ A, const u16* __restrict__ Bw,
    void* __restrict__ Cv, const float* __restrict__ bias,
    int M, int N, int K) {
  __shared__ short As[2][128 * 32];
  __shared__ short Bs[2][128 * 32];
  const int t    = threadIdx.x;
  const int w    = t >> 6;
  const int ln15 = t & 15;
  const int lg   = (t >> 4) & 3;
  const int wr   = w >> 1, wc = w & 1;

  // XCD-aware block remap (nwg % 8 == 0 for all launches here)
  const int nwgx = gridDim.x;
  const int lin  = blockIdx.y * nwgx + blockIdx.x;
  const int cpx  = (nwgx * gridDim.y) >> 3;
  const int lin2 = (lin & 7) * cpx + (lin >> 3);
  const int m0   = (lin2 / nwgx) * 128;
  const int n0   = (lin2 % nwgx) * 128;

  const int srow = t >> 2;
  const int scol = (t & 3) * 8;
  const u16* gA = A + (size_t)(m0 + srow) * K + scol;
  const u16* gB = Bw + (size_t)(n0 + srow) * K + scol;
  const int lofs = w * 512;  // wave-uniform LDS base (lane adds 16B slot)

  f32x4_t acc[4][4] = {};

#define GSTAGE(buf, k0)                                                        \
  do {                                                                         \
    gld16(gA + (k0), &As[buf][lofs]);                                          \
    gld16(gA + (size_t)64 * K + (k0), &As[buf][lofs + 2048]);                  \
    gld16(gB + (k0), &Bs[buf][lofs]);                                          \
    gld16(gB + (size_t)64 * K + (k0), &Bs[buf][lofs + 2048]);                  \
  } while (0)

  const int nk = K >> 5;
  GSTAGE(0, 0);
  int cur = 0;

  for (int ki = 0; ki < nk; ++ki) {
    asm volatile("s_barrier" ::: "memory");  // all waves done reading buf^1
    if (ki + 1 < nk) {
      GSTAGE(cur ^ 1, (ki + 1) * 32);
      asm volatile("s_waitcnt vmcnt(4)" ::: "memory");  // tile ki landed
    } else {
      asm volatile("s_waitcnt vmcnt(0)" ::: "memory");
    }
    asm volatile("s_barrier" ::: "memory");  // buf[cur] ready for all waves

    short8_t af[4], bf[4];
#pragma unroll
    for (int i = 0; i < 4; ++i) {
      af[i] = *reinterpret_cast<const short8_t*>(
          &As[cur][(wr * 64 + i * 16 + ln15) * 32 + 8 * lg]);
      bf[i] = *reinterpret_cast<const short8_t*>(
          &Bs[cur][(wc * 64 + i * 16 + ln15) * 32 + 8 * lg]);
    }
#pragma unroll
    for (int i = 0; i < 4; ++i)
#pragma unroll
      for (int j = 0; j < 4; ++j)
        acc[i][j] = __builtin_amdgcn_mfma_f32_16x16x32_bf16(
            af[i], bf[j], acc[i][j], 0, 0, 0);
    cur ^= 1;
  }
#undef GSTAGE

  if (F32OUT) {
    float* C = reinterpret_cast<float*>(Cv);
#pragma unroll
    for (int i = 0; i < 4; ++i)
#pragma unroll
      for (int j = 0; j < 4; ++j) {
        const int col = n0 + wc * 64 + j * 16 + ln15;
        const float bv = bias ? bias[col] : 0.0f;
#pragma unroll
        for (int r = 0; r < 4; ++r) {
          const int row = m0 + wr * 64 + i * 16 + lg * 4 + r;
          C[(size_t)row * N + col] = acc[i][j][r] + bv;
        }
      }
  } else {
    u16* C = reinterpret_cast<u16*>(Cv);
#pragma unroll
    for (int i = 0; i < 4; ++i)
#pragma unroll
      for (int j = 0; j < 4; ++j) {
        const int col = n0 + wc * 64 + j * 16 + ln15;
#pragma unroll
        for (int r = 0; r < 4; ++r) {
          const int row = m0 + wr * 64 + i * 16 + lg * 4 + r;
          C[(size_t)row * N + col] = f2bf(acc[i][j][r]);
        }
      }
  }
}

// ---------------- causal flash attention, swapped-QK^T, paired KV tiles -----
// r9 structure (4 waves, 16 q-rows/wave, all layouts r3/r8-verified) but
// TWO 64-row KV tiles per iteration using the two LDS buffers as a pair:
// halves barrier/vmcnt count and online-softmax updates for the critical
// (heaviest-qt) blocks. Tail: solo diagonal tile when qt is even.
__global__ __launch_bounds__(256, 4) void k_attn2(const u16* __restrict__ QKV,
                                                  u16* __restrict__ ctx) {
  __shared__ u16 Ks[2][64 * 64];
  __shared__ u16 Vs[2][64 * 64];

  const int t    = threadIdx.x;
  const int w    = t >> 6;
  const int l    = t & 63;
  const int ln15 = t & 15;
  const int lg   = (l >> 4) & 3;

  // LPT: heaviest qt dispatched first
  const int qt = 31 - blockIdx.y;
  const int bh = blockIdx.x;
  const int b  = bh >> 4, h = bh & 15;

  const u16* KVb = QKV + (size_t)b * S_LEN * E3 + h * HD;
  const u16* Kg  = KVb + 1024;
  const u16* Vg  = KVb + 2048;
  const int qrow = qt * 64 + w * 16;
  const int qg   = qrow + ln15;   // this lane's q row (softmax ownership)

  // Q fragments (B-operand): lane (ln15,lg): Q[qrow+ln15][32*sd + 8*lg ..+7]
  short8_t qf[2];
  {
    const u16* qp = KVb + (size_t)(qrow + ln15) * E3 + 8 * lg;
    qf[0] = *reinterpret_cast<const short8_t*>(qp);
    qf[1] = *reinterpret_cast<const short8_t*>(qp + 32);
  }

  // staging address components (r8-verified)
  const int krow_lo = l >> 3;                    // row&7 of K stage row
  const int kcol    = 8 * ((l & 7) ^ krow_lo);   // pre-swizzled source col
  const int vkv     = l >> 1;                    // 0..31
  const int vcol    = 16 * w + 8 * (l & 1);      // dc=w chunk

  // K-frag read offsets (swizzled): chunk XOR with ln15&7
  const int kx  = 8 * (ln15 & 7);
  const int kc0 = (8 * lg) ^ kx;         // sd=0
  const int kc1 = (32 + 8 * lg) ^ kx;    // sd=1

#define STAGE(buf, kv0)                                                        \
  do {                                                                         \
    gld16(Kg + (size_t)((kv0) + 16 * w + krow_lo) * E3 + kcol,                 \
          &Ks[buf][1024 * w]);                                                 \
    gld16(Kg + (size_t)((kv0) + 16 * w + 8 + krow_lo) * E3 + kcol,             \
          &Ks[buf][1024 * w + 512]);                                           \
    gld16(Vg + (size_t)((kv0) + vkv) * E3 + vcol, &Vs[buf][1024 * w]);         \
    gld16(Vg + (size_t)((kv0) + 32 + vkv) * E3 + vcol,                         \
          &Vs[buf][1024 * w + 512]);                                           \
  } while (0)

// 16 tr-reads of V tile in buffer `buf` into vf[4][2][2]
#define VTRREAD(vf, buf)                                                       \
  do {                                                                         \
    const __attribute__((address_space(3))) u16* vp =                          \
        (const __attribute__((address_space(3))) u16*)&Vs[buf][4 * l];         \
    vf[0][0][0]=tr16<0>(vp);    vf[0][0][1]=tr16<512>(vp);                     \
    vf[0][1][0]=tr16<1024>(vp); vf[0][1][1]=tr16<1536>(vp);                    \
    vf[1][0][0]=tr16<2048>(vp); vf[1][0][1]=tr16<2560>(vp);                    \
    vf[1][1][0]=tr16<3072>(vp); vf[1][1][1]=tr16<3584>(vp);                    \
    vf[2][0][0]=tr16<4096>(vp); vf[2][0][1]=tr16<4608>(vp);                    \
    vf[2][1][0]=tr16<5120>(vp); vf[2][1][1]=tr16<5632>(vp);                    \
    vf[3][0][0]=tr16<6144>(vp); vf[3][0][1]=tr16<6656>(vp);                    \
    vf[3][1][0]=tr16<7168>(vp); vf[3][1][1]=tr16<7680>(vp);                    \
  } while (0)

// S^T for one tile from Ks[buf] into tacc (r5-verified fragment math)
#define QKTILE(tacc, buf)                                                      \
  do {                                                                         \
    _Pragma("unroll")                                                          \
    for (int ks = 0; ks < 4; ++ks) {                                           \
      const int R = 16 * ks + ln15;                                            \
      short8_t kf0 = *reinterpret_cast<const short8_t*>(&Ks[buf][R * 64 + kc0]);\
      short8_t kf1 = *reinterpret_cast<const short8_t*>(&Ks[buf][R * 64 + kc1]);\
      f32x4_t a = {0.f, 0.f, 0.f, 0.f};                                        \
      a = __builtin_amdgcn_mfma_f32_16x16x32_bf16(kf0, qf[0], a, 0, 0, 0);     \
      a = __builtin_amdgcn_mfma_f32_16x16x32_bf16(kf1, qf[1], a, 0, 0, 0);     \
      tacc[ks] = a;                                                            \
    }                                                                          \
  } while (0)

// causal mask for tile at base kvb (r5-verified formula)
#define MASK(tacc, kvb)                                                        \
  do {                                                                         \
    _Pragma("unroll")                                                          \
    for (int ks = 0; ks < 4; ++ks)                                             \
      _Pragma("unroll")                                                        \
      for (int r = 0; r < 4; ++r)                                              \
        if ((kvb) + 16 * ks + 4 * lg + r > qg) tacc[ks][r] = -3e38f;           \
  } while (0)

// exp pass: tacc -> p, accumulate rs
#define EXPP(p, tacc)                                                          \
  do {                                                                         \
    _Pragma("unroll")                                                          \
    for (int ks = 0; ks < 4; ++ks)                                             \
      _Pragma("unroll")                                                        \
      for (int r = 0; r < 4; ++r) {                                            \
        const float pv = exp2f(fmaf(tacc[ks][r], L2E, -nmL));                  \
        p[ks][r] = pv;                                                         \
        rs += pv;                                                              \
      }                                                                        \
  } while (0)

// pack p -> pf[2] (r8-verified cvt_pk path)
#define PACK(pf, p)                                                            \
  do {                                                                         \
    _Pragma("unroll")                                                          \
    for (int s2 = 0; s2 < 2; ++s2) {                                           \
      u32x4_t pu;                                                              \
      pu[0] = pkbf(p[2 * s2][0], p[2 * s2][1]);                                \
      pu[1] = pkbf(p[2 * s2][2], p[2 * s2][3]);                                \
      pu[2] = pkbf(p[2 * s2 + 1][0], p[2 * s2 + 1][1]);                        \
      pu[3] = pkbf(p[2 * s2 + 1][2], p[2 * s2 + 1][3]);                        \
      pf[s2] = __builtin_bit_cast(short8_t, pu);                               \
    }                                                                          \
  } while (0)

// PV accumulate: o += P(pf) * V(vf)
#define PV(pf, vf)                                                             \
  do {                                                                         \
    _Pragma("unroll")                                                          \
    for (int nt = 0; nt < 4; ++nt)                                             \
      _Pragma("unroll")                                                        \
      for (int s2 = 0; s2 < 2; ++s2) {                                         \
        short8_t bv = __builtin_shufflevector(vf[nt][s2][0], vf[nt][s2][1],    \
                                              0, 1, 2, 3, 4, 5, 6, 7);         \
        o[nt] = __builtin_amdgcn_mfma_f32_16x16x32_bf16(pf[s2], bv, o[nt],     \
                                                        0, 0, 0);              \
      }                                                                        \
  } while (0)

  f32x4_t o[4] = {};
  float mrow = -3e38f, lrow = 0.0f;

  for (int kv0 = 0; kv0 <= qt * 64; kv0 += 128) {
    const int t0   = kv0 >> 6;           // first tile index (even)
    const bool two = (t0 + 1 <= qt);     // wave-uniform

    asm volatile("s_barrier" ::: "memory");  // all waves done reading prev pair
    STAGE(0, kv0);
    if (two) STAGE(1, kv0 + 64);
    asm volatile("s_waitcnt vmcnt(0)" ::: "memory");
    asm volatile("s_barrier" ::: "memory");  // pair ready for all waves

    // ---- tile A tr-reads early (hide under both QK^T + softmax) ----
    s4v vfA[4][2][2];
    VTRREAD(vfA, 0);

    // ---- S^T both tiles ----
    f32x4_t ta[4], tb[4];
    __builtin_amdgcn_s_setprio(1);
    QKTILE(ta, 0);
    if (two) QKTILE(tb, 1);
    __builtin_amdgcn_s_setprio(0);

    // ---- causal mask: A is diagonal only in solo case; B when t0+1==qt ----
    if (!two) MASK(ta, kv0);
    if (two && (t0 + 1 == qt)) MASK(tb, kv0 + 64);

    // ---- merged online softmax over up to 128 kv ----
    float rm = fmaxf(
        fmaxf(fmaxf(fmaxf(ta[0][0], ta[0][1]), fmaxf(ta[0][2], ta[0][3])),
              fmaxf(fmaxf(ta[1][0], ta[1][1]), fmaxf(ta[1][2], ta[1][3]))),
        fmaxf(fmaxf(fmaxf(ta[2][0], ta[2][1]), fmaxf(ta[2][2], ta[2][3])),
              fmaxf(fmaxf(ta[3][0], ta[3][1]), fmaxf(ta[3][2], ta[3][3]))));
    if (two) {
      rm = fmaxf(rm, fmaxf(
          fmaxf(fmaxf(fmaxf(tb[0][0], tb[0][1]), fmaxf(tb[0][2], tb[0][3])),
                fmaxf(fmaxf(tb[1][0], tb[1][1]), fmaxf(tb[1][2], tb[1][3]))),
          fmaxf(fmaxf(fmaxf(tb[2][0], tb[2][1]), fmaxf(tb[2][2], tb[2][3])),
                fmaxf(fmaxf(tb[3][0], tb[3][1]), fmaxf(tb[3][2], tb[3][3])))));
    }
    rm = fmaxf(rm, __shfl_xor(rm, 16, 64));
    rm = fmaxf(rm, __shfl_xor(rm, 32, 64));

    // THR=0 exact-skip: skipped rescale would multiply by exactly 1.0
    if (__any(rm > mrow)) {
      const float nm = fmaxf(mrow, rm);
      const float sc = exp2f((mrow - nm) * L2E);
      mrow = nm;
      lrow *= sc;
#pragma unroll
      for (int r = 0; r < 4; ++r) {
        const float so = __shfl(sc, 20 * lg + r, 64);
#pragma unroll
        for (int nt = 0; nt < 4; ++nt) o[nt][r] *= so;
      }
    }

    const float nmL = mrow * L2E;
    float rs = 0.0f;
    float pA[4][4];
    EXPP(pA, ta);
    short8_t pfA[2];
    PACK(pfA, pA);
    short8_t pfB[2];
    if (two) {
      float pB[4][4];
      EXPP(pB, tb);
      PACK(pfB, pB);
    }
    rs += __shfl_xor(rs, 16, 64);
    rs += __shfl_xor(rs, 32, 64);
    lrow += rs;

    // ---- PV tile A ----
    asm volatile("s_waitcnt lgkmcnt(0)");
    __builtin_amdgcn_sched_barrier(0);
    __builtin_amdgcn_s_setprio(1);
    PV(pfA, vfA);
    __builtin_amdgcn_s_setprio(0);

    // ---- PV tile B ----
    if (two) {
      s4v vfB[4][2][2];
      VTRREAD(vfB, 1);
      asm volatile("s_waitcnt lgkmcnt(0)");
      __builtin_amdgcn_sched_barrier(0);
      __builtin_amdgcn_s_setprio(1);
      PV(pfB, vfB);
      __builtin_amdgcn_s_setprio(0);
    }
  }
#undef STAGE
#undef VTRREAD
#undef QKTILE
#undef MASK
#undef EXPP
#undef PACK
#undef PV

  // ---- epilogue: normalize and write ctx ----
  const float linv = 1.0f / lrow;
#pragma unroll
  for (int r = 0; r < 4; ++r) {
    const float li = __shfl(linv, 20 * lg + r, 64);
    u16* op = ctx + (size_t)(b * S_LEN + qrow + 4 * lg + r) * EMB + h * HD;
#pragma unroll
    for (int nt = 0; nt < 4; ++nt)
      op[nt * 16 + ln15] = f2bf(o[nt][r] * li);
  }
}

// ---------------------------------------------------------------------------
extern "C" void kernel_launch(void* const* d_in, const int* in_sizes, int n_in,
                              void* d_out, int out_size, void* d_ws, size_t ws_size,
                              hipStream_t stream) {
  const float* x  = (const float*)d_in[0];
  const float* Wq = (const float*)d_in[1];
  const float* Wk = (const float*)d_in[2];
  const float* Wv = (const float*)d_in[3];
  const float* Wo = (const float*)d_in[4];
  const float* bo = (const float*)d_in[5];

  u16* ws   = (u16*)d_ws;
  u16* xb   = ws;                               // 4096*1024
  u16* wcat = xb + (size_t)MR * EMB;            // 3*1024*1024 (Wq|Wk|Wv rows)
  u16* wob  = wcat + (size_t)3 * EMB * EMB;     // 1024*1024
  u16* qkv  = wob + (size_t)EMB * EMB;          // 4096*3072
  u16* ctxb = qkv + (size_t)MR * E3;            // 4096*1024

  // fused fp32 -> bf16 (x | Wq*0.125 | Wk | Wv | Wo), dest contiguous at xb
  k_cvt_all<<<8192, 256, 0, stream>>>(x, Wq, Wk, Wv, Wo, xb);

  // QKV = x @ Wcat^T  (M=4096, N=3072, K=1024), bf16 out
  k_gemm_bt<false><<<dim3(E3 / 128, MR / 128), 256, 0, stream>>>(
      xb, wcat, qkv, nullptr, MR, E3, EMB);

  // causal flash attention -> ctx (bf16)
  k_attn2<<<dim3(BATCH * NH, 32), 256, 0, stream>>>(qkv, ctxb);

  // out = ctx @ Wo^T + bo  (fp32 out)
  k_gemm_bt<true><<<dim3(EMB / 128, MR / 128), 256, 0, stream>>>(
      ctxb, wob, d_out, bo, MR, EMB, EMB);
}

// Round 12
// 119.738 us; speedup vs baseline: 1.0194x; 1.0194x over previous
//
#include <hip/hip_runtime.h>
#include <hip/hip_bf16.h>

typedef __attribute__((ext_vector_type(8))) short short8_t;
typedef __attribute__((ext_vector_type(4))) short s4v;
typedef __attribute__((ext_vector_type(4))) float f32x4_t;
typedef __attribute__((ext_vector_type(4))) unsigned u32x4_t;
using u16 = unsigned short;

constexpr int S_LEN = 2048;
constexpr int EMB   = 1024;
constexpr int NH    = 16;
constexpr int HD    = 64;
constexpr int BATCH = 2;
constexpr int MR    = BATCH * S_LEN;  // 4096
constexpr int E3    = 3 * EMB;        // 3072

#define L2E 1.44269504f

__device__ __forceinline__ u16 f2bf(float f) {
  unsigned u = __builtin_bit_cast(unsigned, f);
  unsigned r = 0x7fffu + ((u >> 16) & 1u);
  return (u16)((u + r) >> 16);
}

// packed f32x2 -> bf16x2 via intrinsic (RNE, compiler emits v_cvt_pk_bf16_f32)
__device__ __forceinline__ unsigned pkbf(float a, float b) {
  __hip_bfloat162 h = __float22bfloat162_rn(make_float2(a, b));
  unsigned u;
  __builtin_memcpy(&u, &h, 4);
  return u;
}

__device__ __forceinline__ void gld16(const void* g, void* l) {
  __builtin_amdgcn_global_load_lds(
      (const __attribute__((address_space(1))) void*)g,
      (__attribute__((address_space(3))) void*)l, 16, 0, 0);
}

// hardware transpose read. Canonical per-lane address = base + 8B*lane:
// lane l, elem j <- lds_elem[64*(l>>4) + 16*j + (l&15)] (+ offset/2 elems).
template <int OFF>
__device__ __forceinline__ s4v tr16(const __attribute__((address_space(3))) u16* p) {
  s4v d;
  asm volatile("ds_read_b64_tr_b16 %0, %1 offset:%2"
               : "=v"(d) : "v"(p), "n"(OFF));
  return d;
}

// ---------------- fused fp32 -> bf16 conversion ----------------------------
// dest layout (contiguous in ws): xb(4M) | Wq(1M,*0.125) | Wk | Wv | Wo
__global__ void k_cvt_all(const float* __restrict__ x, const float* __restrict__ Wq,
                          const float* __restrict__ Wk, const float* __restrict__ Wv,
                          const float* __restrict__ Wo, u16* __restrict__ out) {
  int i = blockIdx.x * 256 + threadIdx.x;  // float4 index, total 2M
  const float* src;
  int j;
  float sc = 1.0f;
  if (i < (1 << 20)) {
    src = x; j = i;
  } else {
    int jj = i - (1 << 20);
    int r = jj >> 18;
    j = jj & ((1 << 18) - 1);
    src = (r == 0) ? Wq : (r == 1) ? Wk : (r == 2) ? Wv : Wo;
    if (r == 0) sc = 0.125f;  // fold softmax 1/sqrt(64)
  }
  float4 v = reinterpret_cast<const float4*>(src)[j];
  ushort4 o;
  o.x = f2bf(v.x * sc); o.y = f2bf(v.y * sc);
  o.z = f2bf(v.z * sc); o.w = f2bf(v.w * sc);
  reinterpret_cast<ushort4*>(out)[i] = o;
}

// ---------------- bf16 GEMM 256x256 tile, BK=64, 8 waves (QKV) -------------
// C = A @ B^T. A:(M,1024) row-major bf16, Bw:(N,1024) row-major bf16,
// C:(M,N) bf16. LDS tiles [256][64] with chunk-XOR swizzle (attn-verified:
// logical 16B-chunk c of row r stored at position c^(r&7); staged via
// pre-swizzled global col, read via XOR'd offset; 0 bank conflicts).
// Pipeline: r9-verified counted-vmcnt double buffer.
__global__ __launch_bounds__(512, 1) void k_gemm256(
    const u16* __restrict__ A, const u16* __restrict__ Bw,
    u16* __restrict__ C, int M, int N) {
  constexpr int K = 1024;
  __shared__ u16 Ab[2][16384];   // [256][64]
  __shared__ u16 Bb[2][16384];

  const int t    = threadIdx.x;
  const int ww   = t >> 6;         // wave 0..7
  const int l    = t & 63;
  const int ln15 = t & 15;
  const int lg   = (t >> 4) & 3;
  const int wr   = ww >> 2;        // 0..1 (M half)
  const int wc   = ww & 3;         // 0..3 (N quarter)

  // XCD-aware remap: nwg = (N/256)*(M/256) = 12*16 = 192, %8==0 -> bijective
  const int nwgx = gridDim.x;
  const int lin  = blockIdx.y * nwgx + blockIdx.x;
  const int cpx  = (nwgx * gridDim.y) >> 3;
  const int lin2 = (lin & 7) * cpx + (lin >> 3);
  const int m0   = (lin2 / nwgx) * 256;
  const int n0   = (lin2 % nwgx) * 256;

  // staging: round i stages tile rows 64i..64i+63; thread t handles
  // row-in-round srow = t>>3, logical chunk (t&7)^(srow&7) (pre-swizzle so
  // linear LDS dest yields swizzled layout). LDS dest wave-uniform base.
  const int srow = t >> 3;                       // 0..63
  const int rlo  = (t >> 3) & 7;
  const int scol = 8 * ((t & 7) ^ rlo);          // source col elems

  // read offsets: logical chunk (4*kh+lg) of row r at position ^(r&7)
  const int kx  = 8 * (ln15 & 7);
  const int kc0 = (8 * lg) ^ kx;        // kh=0
  const int kc1 = (32 + 8 * lg) ^ kx;   // kh=1

  f32x4_t acc[8][4] = {};

#define GST256(buf, ki)                                                        \
  do {                                                                         \
    _Pragma("unroll")                                                          \
    for (int i = 0; i < 4; ++i)                                                \
      gld16(A + (size_t)(m0 + 64 * i + srow) * K + 64 * (ki) + scol,           \
            &Ab[buf][i * 4096 + ww * 512]);                                    \
    _Pragma("unroll")                                                          \
    for (int i = 0; i < 4; ++i)                                                \
      gld16(Bw + (size_t)(n0 + 64 * i + srow) * K + 64 * (ki) + scol,          \
            &Bb[buf][i * 4096 + ww * 512]);                                    \
  } while (0)

  constexpr int nk = K / 64;   // 16
  GST256(0, 0);
  int cur = 0;

  for (int ki = 0; ki < nk; ++ki) {
    asm volatile("s_barrier" ::: "memory");   // all waves done reading buf^1
    if (ki + 1 < nk) {
      GST256(cur ^ 1, ki + 1);
      asm volatile("s_waitcnt vmcnt(8)" ::: "memory");  // tile ki landed
    } else {
      asm volatile("s_waitcnt vmcnt(0)" ::: "memory");
    }
    asm volatile("s_barrier" ::: "memory");   // buf[cur] ready for all waves

#pragma unroll
    for (int kh = 0; kh < 2; ++kh) {
      const int kc = kh ? kc1 : kc0;
      short8_t af[8], bf[4];
#pragma unroll
      for (int mi = 0; mi < 8; ++mi)
        af[mi] = *reinterpret_cast<const short8_t*>(
            &Ab[cur][(wr * 128 + 16 * mi + ln15) * 64 + kc]);
#pragma unroll
      for (int ni = 0; ni < 4; ++ni)
        bf[ni] = *reinterpret_cast<const short8_t*>(
            &Bb[cur][(wc * 64 + 16 * ni + ln15) * 64 + kc]);
      __builtin_amdgcn_s_setprio(1);
#pragma unroll
      for (int mi = 0; mi < 8; ++mi)
#pragma unroll
        for (int ni = 0; ni < 4; ++ni)
          acc[mi][ni] = __builtin_amdgcn_mfma_f32_16x16x32_bf16(
              af[mi], bf[ni], acc[mi][ni], 0, 0, 0);
      __builtin_amdgcn_s_setprio(0);
    }
    cur ^= 1;
  }
#undef GST256

  // epilogue: C[row = m0+wr*128+16mi+4lg+rr][col = n0+wc*64+16ni+ln15]
#pragma unroll
  for (int mi = 0; mi < 8; ++mi) {
#pragma unroll
    for (int ni = 0; ni < 4; ++ni) {
      const int col = n0 + wc * 64 + 16 * ni + ln15;
#pragma unroll
      for (int rr = 0; rr < 4; ++rr) {
        const int row = m0 + wr * 128 + 16 * mi + 4 * lg + rr;
        C[(size_t)row * N + col] = f2bf(acc[mi][ni][rr]);
      }
    }
  }
}

// ---------------- bf16 GEMM, B^T input, 128x128 tile (out-proj) ------------
// 2-phase double-buffered staging (r9-verified). T1 XCD swizzle.
template <bool F32OUT>
__global__ __launch_bounds__(256) void k_gemm_bt(
    const u16* __restrict__ A, const u16* __restrict__ Bw,
    void* __restrict__ Cv, const float* __restrict__ bias,
    int M, int N, int K) {
  __shared__ short As[2][128 * 32];
  __shared__ short Bs[2][128 * 32];
  const int t    = threadIdx.x;
  const int w    = t >> 6;
  const int ln15 = t & 15;
  const int lg   = (t >> 4) & 3;
  const int wr   = w >> 1, wc = w & 1;

  const int nwgx = gridDim.x;
  const int lin  = blockIdx.y * nwgx + blockIdx.x;
  const int cpx  = (nwgx * gridDim.y) >> 3;
  const int lin2 = (lin & 7) * cpx + (lin >> 3);
  const int m0   = (lin2 / nwgx) * 128;
  const int n0   = (lin2 % nwgx) * 128;

  const int srow = t >> 2;
  const int scol = (t & 3) * 8;
  const u16* gA = A + (size_t)(m0 + srow) * K + scol;
  const u16* gB = Bw + (size_t)(n0 + srow) * K + scol;
  const int lofs = w * 512;

  f32x4_t acc[4][4] = {};

#define GSTAGE(buf, k0)                                                        \
  do {                                                                         \
    gld16(gA + (k0), &As[buf][lofs]);                                          \
    gld16(gA + (size_t)64 * K + (k0), &As[buf][lofs + 2048]);                  \
    gld16(gB + (k0), &Bs[buf][lofs]);                                          \
    gld16(gB + (size_t)64 * K + (k0), &Bs[buf][lofs + 2048]);                  \
  } while (0)

  const int nk = K >> 5;
  GSTAGE(0, 0);
  int cur = 0;

  for (int ki = 0; ki < nk; ++ki) {
    asm volatile("s_barrier" ::: "memory");
    if (ki + 1 < nk) {
      GSTAGE(cur ^ 1, (ki + 1) * 32);
      asm volatile("s_waitcnt vmcnt(4)" ::: "memory");
    } else {
      asm volatile("s_waitcnt vmcnt(0)" ::: "memory");
    }
    asm volatile("s_barrier" ::: "memory");

    short8_t af[4], bf[4];
#pragma unroll
    for (int i = 0; i < 4; ++i) {
      af[i] = *reinterpret_cast<const short8_t*>(
          &As[cur][(wr * 64 + i * 16 + ln15) * 32 + 8 * lg]);
      bf[i] = *reinterpret_cast<const short8_t*>(
          &Bs[cur][(wc * 64 + i * 16 + ln15) * 32 + 8 * lg]);
    }
#pragma unroll
    for (int i = 0; i < 4; ++i)
#pragma unroll
      for (int j = 0; j < 4; ++j)
        acc[i][j] = __builtin_amdgcn_mfma_f32_16x16x32_bf16(
            af[i], bf[j], acc[i][j], 0, 0, 0);
    cur ^= 1;
  }
#undef GSTAGE

  if (F32OUT) {
    float* C = reinterpret_cast<float*>(Cv);
#pragma unroll
    for (int i = 0; i < 4; ++i)
#pragma unroll
      for (int j = 0; j < 4; ++j) {
        const int col = n0 + wc * 64 + j * 16 + ln15;
        const float bv = bias ? bias[col] : 0.0f;
#pragma unroll
        for (int r = 0; r < 4; ++r) {
          const int row = m0 + wr * 64 + i * 16 + lg * 4 + r;
          C[(size_t)row * N + col] = acc[i][j][r] + bv;
        }
      }
  } else {
    u16* C = reinterpret_cast<u16*>(Cv);
#pragma unroll
    for (int i = 0; i < 4; ++i)
#pragma unroll
      for (int j = 0; j < 4; ++j) {
        const int col = n0 + wc * 64 + j * 16 + ln15;
#pragma unroll
        for (int r = 0; r < 4; ++r) {
          const int row = m0 + wr * 64 + i * 16 + lg * 4 + r;
          C[(size_t)row * N + col] = f2bf(acc[i][j][r]);
        }
      }
  }
}

// ---------------- causal flash attention, swapped-QK^T (r9-exact) ----------
__global__ __launch_bounds__(256, 4) void k_attn2(const u16* __restrict__ QKV,
                                                  u16* __restrict__ ctx) {
  __shared__ u16 Ks[2][64 * 64];
  __shared__ u16 Vs[2][64 * 64];

  const int t    = threadIdx.x;
  const int w    = t >> 6;
  const int l    = t & 63;
  const int ln15 = t & 15;
  const int lg   = (l >> 4) & 3;

  const int qt = 31 - blockIdx.y;
  const int bh = blockIdx.x;
  const int b  = bh >> 4, h = bh & 15;

  const u16* KVb = QKV + (size_t)b * S_LEN * E3 + h * HD;
  const u16* Kg  = KVb + 1024;
  const u16* Vg  = KVb + 2048;
  const int qrow = qt * 64 + w * 16;

  short8_t qf[2];
  {
    const u16* qp = KVb + (size_t)(qrow + ln15) * E3 + 8 * lg;
    qf[0] = *reinterpret_cast<const short8_t*>(qp);
    qf[1] = *reinterpret_cast<const short8_t*>(qp + 32);
  }

  const int krow_lo = l >> 3;
  const int kcol    = 8 * ((l & 7) ^ krow_lo);
  const int vkv     = l >> 1;
  const int vcol    = 16 * w + 8 * (l & 1);

  const int kx  = 8 * (ln15 & 7);
  const int kc0 = (8 * lg) ^ kx;
  const int kc1 = (32 + 8 * lg) ^ kx;

#define STAGE(buf, kv0)                                                        \
  do {                                                                         \
    gld16(Kg + (size_t)((kv0) + 16 * w + krow_lo) * E3 + kcol,                 \
          &Ks[buf][1024 * w]);                                                 \
    gld16(Kg + (size_t)((kv0) + 16 * w + 8 + krow_lo) * E3 + kcol,             \
          &Ks[buf][1024 * w + 512]);                                           \
    gld16(Vg + (size_t)((kv0) + vkv) * E3 + vcol, &Vs[buf][1024 * w]);         \
    gld16(Vg + (size_t)((kv0) + 32 + vkv) * E3 + vcol,                         \
          &Vs[buf][1024 * w + 512]);                                           \
  } while (0)

  f32x4_t o[4] = {};
  float mrow = -3e38f, lrow = 0.0f;
  const int nt_tiles = qt + 1;

  STAGE(0, 0);
  int cur = 0;

  for (int kvt = 0; kvt < nt_tiles; ++kvt) {
    const int kv0 = kvt * 64;
    asm volatile("s_barrier" ::: "memory");
    if (kvt + 1 < nt_tiles) {
      STAGE(cur ^ 1, kv0 + 64);
      asm volatile("s_waitcnt vmcnt(4)" ::: "memory");
    } else {
      asm volatile("s_waitcnt vmcnt(0)" ::: "memory");
    }
    asm volatile("s_barrier" ::: "memory");

    const __attribute__((address_space(3))) u16* vp =
        (const __attribute__((address_space(3))) u16*)&Vs[cur][4 * l];
    s4v vf[4][2][2];
#pragma unroll
    for (int nt = 0; nt < 4; ++nt) {
      if (nt == 0) { vf[0][0][0]=tr16<0>(vp);    vf[0][0][1]=tr16<512>(vp);
                     vf[0][1][0]=tr16<1024>(vp); vf[0][1][1]=tr16<1536>(vp); }
      if (nt == 1) { vf[1][0][0]=tr16<2048>(vp); vf[1][0][1]=tr16<2560>(vp);
                     vf[1][1][0]=tr16<3072>(vp); vf[1][1][1]=tr16<3584>(vp); }
      if (nt == 2) { vf[2][0][0]=tr16<4096>(vp); vf[2][0][1]=tr16<4608>(vp);
                     vf[2][1][0]=tr16<5120>(vp); vf[2][1][1]=tr16<5632>(vp); }
      if (nt == 3) { vf[3][0][0]=tr16<6144>(vp); vf[3][0][1]=tr16<6656>(vp);
                     vf[3][1][0]=tr16<7168>(vp); vf[3][1][1]=tr16<7680>(vp); }
    }

    f32x4_t tacc[4];
    __builtin_amdgcn_s_setprio(1);
#pragma unroll
    for (int ks = 0; ks < 4; ++ks) {
      const int R = 16 * ks + ln15;
      short8_t kf0 = *reinterpret_cast<const short8_t*>(&Ks[cur][R * 64 + kc0]);
      short8_t kf1 = *reinterpret_cast<const short8_t*>(&Ks[cur][R * 64 + kc1]);
      f32x4_t a = {0.f, 0.f, 0.f, 0.f};
      a = __builtin_amdgcn_mfma_f32_16x16x32_bf16(kf0, qf[0], a, 0, 0, 0);
      a = __builtin_amdgcn_mfma_f32_16x16x32_bf16(kf1, qf[1], a, 0, 0, 0);
      tacc[ks] = a;
    }
    __builtin_amdgcn_s_setprio(0);

    if (kvt == qt) {
      const int qg = qrow + ln15;
#pragma unroll
      for (int ks = 0; ks < 4; ++ks)
#pragma unroll
        for (int r = 0; r < 4; ++r)
          if (kv0 + 16 * ks + 4 * lg + r > qg) tacc[ks][r] = -3e38f;
    }

    float rm = fmaxf(
        fmaxf(fmaxf(fmaxf(tacc[0][0], tacc[0][1]), fmaxf(tacc[0][2], tacc[0][3])),
              fmaxf(fmaxf(tacc[1][0], tacc[1][1]), fmaxf(tacc[1][2], tacc[1][3]))),
        fmaxf(fmaxf(fmaxf(tacc[2][0], tacc[2][1]), fmaxf(tacc[2][2], tacc[2][3])),
              fmaxf(fmaxf(tacc[3][0], tacc[3][1]), fmaxf(tacc[3][2], tacc[3][3]))));
    rm = fmaxf(rm, __shfl_xor(rm, 16, 64));
    rm = fmaxf(rm, __shfl_xor(rm, 32, 64));

    if (__any(rm > mrow)) {
      const float nm = fmaxf(mrow, rm);
      const float sc = exp2f((mrow - nm) * L2E);
      mrow = nm;
      lrow *= sc;
#pragma unroll
      for (int r = 0; r < 4; ++r) {
        const float so = __shfl(sc, 20 * lg + r, 64);
#pragma unroll
        for (int nt = 0; nt < 4; ++nt) o[nt][r] *= so;
      }
    }

    const float nmL = mrow * L2E;
    float p[4][4];
    float rs = 0.0f;
#pragma unroll
    for (int ks = 0; ks < 4; ++ks)
#pragma unroll
      for (int r = 0; r < 4; ++r) {
        const float pv = exp2f(fmaf(tacc[ks][r], L2E, -nmL));
        p[ks][r] = pv;
        rs += pv;
      }
    rs += __shfl_xor(rs, 16, 64);
    rs += __shfl_xor(rs, 32, 64);
    lrow += rs;

    short8_t pf[2];
#pragma unroll
    for (int s2 = 0; s2 < 2; ++s2) {
      u32x4_t pu;
      pu[0] = pkbf(p[2 * s2][0], p[2 * s2][1]);
      pu[1] = pkbf(p[2 * s2][2], p[2 * s2][3]);
      pu[2] = pkbf(p[2 * s2 + 1][0], p[2 * s2 + 1][1]);
      pu[3] = pkbf(p[2 * s2 + 1][2], p[2 * s2 + 1][3]);
      pf[s2] = __builtin_bit_cast(short8_t, pu);
    }

    asm volatile("s_waitcnt lgkmcnt(0)");
    __builtin_amdgcn_sched_barrier(0);

    __builtin_amdgcn_s_setprio(1);
#pragma unroll
    for (int nt = 0; nt < 4; ++nt) {
#pragma unroll
      for (int s2 = 0; s2 < 2; ++s2) {
        short8_t bv = __builtin_shufflevector(vf[nt][s2][0], vf[nt][s2][1],
                                              0, 1, 2, 3, 4, 5, 6, 7);
        o[nt] = __builtin_amdgcn_mfma_f32_16x16x32_bf16(pf[s2], bv, o[nt], 0, 0, 0);
      }
    }
    __builtin_amdgcn_s_setprio(0);
    cur ^= 1;
  }
#undef STAGE

  const float linv = 1.0f / lrow;
#pragma unroll
  for (int r = 0; r < 4; ++r) {
    const float li = __shfl(linv, 20 * lg + r, 64);
    u16* op = ctx + (size_t)(b * S_LEN + qrow + 4 * lg + r) * EMB + h * HD;
#pragma unroll
    for (int nt = 0; nt < 4; ++nt)
      op[nt * 16 + ln15] = f2bf(o[nt][r] * li);
  }
}

// ---------------------------------------------------------------------------
extern "C" void kernel_launch(void* const* d_in, const int* in_sizes, int n_in,
                              void* d_out, int out_size, void* d_ws, size_t ws_size,
                              hipStream_t stream) {
  const float* x  = (const float*)d_in[0];
  const float* Wq = (const float*)d_in[1];
  const float* Wk = (const float*)d_in[2];
  const float* Wv = (const float*)d_in[3];
  const float* Wo = (const float*)d_in[4];
  const float* bo = (const float*)d_in[5];

  u16* ws   = (u16*)d_ws;
  u16* xb   = ws;                               // 4096*1024
  u16* wcat = xb + (size_t)MR * EMB;            // 3*1024*1024 (Wq|Wk|Wv rows)
  u16* wob  = wcat + (size_t)3 * EMB * EMB;     // 1024*1024
  u16* qkv  = wob + (size_t)EMB * EMB;          // 4096*3072
  u16* ctxb = qkv + (size_t)MR * E3;            // 4096*1024

  // fused fp32 -> bf16 (x | Wq*0.125 | Wk | Wv | Wo), dest contiguous at xb
  k_cvt_all<<<8192, 256, 0, stream>>>(x, Wq, Wk, Wv, Wo, xb);

  // QKV = x @ Wcat^T  (M=4096, N=3072, K=1024), bf16 out, 256^2 8-wave
  k_gemm256<<<dim3(E3 / 256, MR / 256), 512, 0, stream>>>(
      xb, wcat, qkv, MR, E3);

  // causal flash attention -> ctx (bf16)
  k_attn2<<<dim3(BATCH * NH, 32), 256, 0, stream>>>(qkv, ctxb);

  // out = ctx @ Wo^T + bo  (fp32 out)
  k_gemm_bt<true><<<dim3(EMB / 128, MR / 128), 256, 0, stream>>>(
      ctxb, wob, d_out, bo, MR, EMB, EMB);
}